// Round 9
// baseline (172.730 us; speedup 1.0000x reference)
//
#include <hip/hip_runtime.h>
#include <math.h>

// Both clouds: 16384 x float2, coords ~ N(0,1).
#define NPTS 16384
#define G    64                 // grid is G x G
#define NB   (G * G)            // 4096 bins
#define CAP  128                // points per bin capacity (central bin E~64)
#define OCAP 2048               // overflow target-list capacity
#define HCAP 16384              // hard (brute-forced) query list capacity per dir
#define BV   5.0f               // grid covers [-BV, BV]^2 (clamped outside)
#define H    0.15625f           // 2*BV/G cell width
#define INVH (1.0f / H)
#define SLICE 1160              // float2 slots per wave slice (9*CAP=1152 fits)

// ws layout:
//   [0, 32768)        cnt[2][NB] uint
//   [32768, 32784)    ovf_cnt[2], hcnt[2] uint
//   [65536, +8 MB)    binned[2][NB][CAP] float2 (cell-sorted)
//   [8454144, +32 KB) ovf[2][OCAP] float2   (overflow TARGETS, scanned by all)
//   [8486912, +256KB) hard[2][HCAP] float2  (queries needing brute force)

__global__ __launch_bounds__(256) void k_zero(unsigned int* __restrict__ cnt,
                                              float* __restrict__ out) {
    int i = blockIdx.x * 256 + threadIdx.x;
    if (i < 2 * NB + 4) cnt[i] = 0u;   // cnt + ovf_cnt + hcnt contiguous
    if (i == 0) out[0] = 0.0f;
}

__global__ __launch_bounds__(256) void k_scatter(
        const float2* __restrict__ pc, const float2* __restrict__ ref,
        unsigned int* __restrict__ cnt, unsigned int* __restrict__ ovf_cnt,
        unsigned int* __restrict__ hcnt,
        float2* __restrict__ binned, float2* __restrict__ ovf,
        float2* __restrict__ hard) {
    int t  = blockIdx.x * 256 + threadIdx.x;   // 0..32767
    int cl = t >> 14;                          // cloud: 0=pc, 1=ref
    int i  = t & (NPTS - 1);
    float2 p = (cl ? ref : pc)[i];
    int bx = (int)floorf((p.x + BV) * INVH); bx = min(max(bx, 0), G - 1);
    int by = (int)floorf((p.y + BV) * INVH); by = min(max(by, 0), G - 1);
    int b = cl * NB + by * G + bx;
    unsigned idx = atomicAdd(&cnt[b], 1u);
    if (idx < CAP) {
        binned[(size_t)b * CAP + idx] = p;
    } else {
        // Target-side supplement (scanned by every k_query wave)...
        unsigned oi = atomicAdd(&ovf_cnt[cl], 1u);
        if (oi < OCAP) ovf[cl * OCAP + oi] = p;
        // ...and query-side: send straight to brute force (exact vs raw arrays).
        unsigned hi = atomicAdd(&hcnt[cl], 1u);
        hard[cl * HCAP + hi] = p;
    }
}

// One wave per (dir, cell), swizzled. Q=2 queries/lane (nq<=128), one pass.
// Scan = 3x3 neighborhood staged in LDS. Lane resolved iff best <= H^2
// (everything outside 3x3 is >= H away -> exact). Unresolved queries are
// ballot-compacted into the hard list for k_brute. No ring machinery.
__global__ __launch_bounds__(256) void k_query(
        const unsigned int* __restrict__ cnt, const unsigned int* __restrict__ ovf_cnt,
        unsigned int* __restrict__ hcnt,
        const float2* __restrict__ binned, const float2* __restrict__ ovf,
        float2* __restrict__ hard, float* __restrict__ out) {
    __shared__ float2 s_pts[4 * SLICE];   // 37120 B: per-wave staging slices
    __shared__ float  s_bsum[4];

    int d    = blockIdx.y;                // query cloud
    int td   = 1 - d;                     // target cloud
    int wave = threadIdx.x >> 6;
    int lane = threadIdx.x & 63;
    int w    = blockIdx.x * 4 + wave;
    float2* my = s_pts + wave * SLICE;
    float sum = 0.0f;

    int c  = (w * 65) & (NB - 1);         // bijective swizzle: spread dense cells
    int cx = c & (G - 1), cy = c >> 6;
    int nq = (int)min(cnt[d * NB + c], (unsigned)CAP);
    if (nq > 0) {
        const unsigned int* tcnt = cnt + td * NB;
        const float2* tbin = binned + (size_t)td * NB * CAP;
        unsigned novf = min(ovf_cnt[td], (unsigned)OCAP);

        // ---- parallel 3x3 count probe (independent loads), then copy to LDS
        int tid9[9], tn9[9], nv = 0;
#pragma unroll
        for (int dy = -1; dy <= 1; ++dy)
#pragma unroll
            for (int dx = -1; dx <= 1; ++dx) {
                int x = cx + dx, y = cy + dy;
                if ((unsigned)x < G && (unsigned)y < G) {
                    tid9[nv] = y * G + x;
                    tn9[nv]  = (int)min(tcnt[y * G + x], (unsigned)CAP);
                    ++nv;
                }
            }
        int nt = 0;
        for (int v = 0; v < nv; ++v) {
            int t = tid9[v], tn = tn9[v];
            for (int i = lane; i < tn; i += 64)
                my[nt + i] = tbin[(size_t)t * CAP + i];   // coalesced
            nt += tn;
        }
        int ntr = (nt + 3) & ~3;
        if (lane < ntr - nt) my[nt + lane] = make_float2(1e30f, 1e30f);

        // ---- 2 queries per lane (slots in-bounds; poison-safe for invalid)
        bool v0 = lane < nq, v1 = (64 + lane) < nq;
        const float2* qbin = binned + (size_t)(d * NB + c) * CAP;
        float2 q0 = qbin[lane];
        float2 q1 = qbin[64 + lane];
        float b0 = INFINITY, b1 = INFINITY;

        // Overflow targets (normally zero) — scanned unconditionally: exact.
        for (unsigned j = 0; j < novf; ++j) {
            float2 tp = ovf[td * OCAP + j];
            float ax = q0.x - tp.x, ay = q0.y - tp.y;
            float bx = q1.x - tp.x, by = q1.y - tp.y;
            b0 = fminf(b0, fmaf(ax, ax, ay * ay));
            b1 = fminf(b1, fmaf(bx, bx, by * by));
        }

        // ---- scan 3x3 from LDS: 4 points/iter, both queries
        const float4* p4 = (const float4*)my;
#pragma unroll 4
        for (int k = 0; k < ntr; k += 4) {
            float4 ab = p4[k >> 1];
            float4 cd = p4[(k >> 1) + 1];
            float x0 = q0.x - ab.x, y0 = q0.y - ab.y;
            float x1 = q0.x - ab.z, y1 = q0.y - ab.w;
            float x2 = q0.x - cd.x, y2 = q0.y - cd.y;
            float x3 = q0.x - cd.z, y3 = q0.y - cd.w;
            float d0 = fmaf(x0, x0, y0 * y0);
            float d1 = fmaf(x1, x1, y1 * y1);
            float d2 = fmaf(x2, x2, y2 * y2);
            float d3 = fmaf(x3, x3, y3 * y3);
            b0 = fminf(b0, fminf(fminf(d0, d1), fminf(d2, d3)));
            float u0 = q1.x - ab.x, w0 = q1.y - ab.y;
            float u1 = q1.x - ab.z, w1 = q1.y - ab.w;
            float u2 = q1.x - cd.x, w2 = q1.y - cd.y;
            float u3 = q1.x - cd.z, w3 = q1.y - cd.w;
            float e0 = fmaf(u0, u0, w0 * w0);
            float e1 = fmaf(u1, u1, w1 * w1);
            float e2 = fmaf(u2, u2, w2 * w2);
            float e3 = fmaf(u3, u3, w3 * w3);
            b1 = fminf(b1, fminf(fminf(e0, e1), fminf(e2, e3)));
        }

        // ---- classify: resolved iff best <= H^2 (exact); else -> hard list
        const float RES = H * H;
        bool r0 = v0 && b0 <= RES, h0 = v0 && !r0;
        bool r1 = v1 && b1 <= RES, h1 = v1 && !r1;
        sum = (r0 ? sqrtf(b0) : 0.0f) + (r1 ? sqrtf(b1) : 0.0f);

        auto append = [&](float2 q, bool pred) {
            unsigned long long mb = __ballot(pred);
            if (mb) {
                int leader = __builtin_ctzll(mb);
                unsigned base = 0;
                if (lane == leader)
                    base = atomicAdd(&hcnt[d], (unsigned)__popcll(mb));
                base = (unsigned)__shfl((int)base, leader, 64);
                if (pred) {
                    int pos = __popcll(mb & ((1ull << lane) - 1ull));
                    hard[d * HCAP + base + pos] = q;
                }
            }
        };
        append(q0, h0);
        append(q1, h1);
    }

    // Wave reduce -> block reduce -> one atomic per block.
#pragma unroll
    for (int off = 32; off > 0; off >>= 1)
        sum += __shfl_down(sum, off, 64);
    if (lane == 0) s_bsum[wave] = sum;
    __syncthreads();
    if (threadIdx.x == 0) {
        float t = s_bsum[0] + s_bsum[1] + s_bsum[2] + s_bsum[3];
        if (t != 0.0f) atomicAdd(out, t);
    }
}

// One wave per hard query: lanes partition ALL 16384 raw targets (coalesced,
// independent loads -> pipelined), butterfly min-reduce, one sqrt per query.
__global__ __launch_bounds__(256) void k_brute(
        const float2* __restrict__ pc, const float2* __restrict__ ref,
        const unsigned int* __restrict__ hcnt, const float2* __restrict__ hard,
        float* __restrict__ out) {
    __shared__ float s_bsum[4];
    int wave = threadIdx.x >> 6;
    int lane = threadIdx.x & 63;
    int W    = blockIdx.x * 4 + wave;     // 1024 waves total
    float sum = 0.0f;

    for (int d = 0; d < 2; ++d) {
        int n = (int)min(hcnt[d], (unsigned)HCAP);
        const float2* tgt = d ? pc : ref;
        for (int qi = W; qi < n; qi += 1024) {
            float2 q = hard[d * HCAP + qi];
            float best = INFINITY;
            for (int j = lane; j < NPTS; j += 64) {   // coalesced across lanes
                float2 tp = tgt[j];
                float dx = q.x - tp.x, dy = q.y - tp.y;
                best = fminf(best, fmaf(dx, dx, dy * dy));
            }
#pragma unroll
            for (int off = 32; off > 0; off >>= 1)
                best = fminf(best, __shfl_xor(best, off, 64));
            if (lane == 0) sum += sqrtf(best);
        }
    }

#pragma unroll
    for (int off = 32; off > 0; off >>= 1)
        sum += __shfl_down(sum, off, 64);
    if (lane == 0) s_bsum[wave] = sum;
    __syncthreads();
    if (threadIdx.x == 0) {
        float t = s_bsum[0] + s_bsum[1] + s_bsum[2] + s_bsum[3];
        if (t != 0.0f) atomicAdd(out, t);
    }
}

extern "C" void kernel_launch(void* const* d_in, const int* in_sizes, int n_in,
                              void* d_out, int out_size, void* d_ws, size_t ws_size,
                              hipStream_t stream) {
    const float2* pc  = (const float2*)d_in[0];  // img_render_points (128*128*2 f32)
    const float2* ref = (const float2*)d_in[1];  // ref contour (16384*2 f32)
    float* out = (float*)d_out;

    char* w = (char*)d_ws;
    unsigned int* cnt     = (unsigned int*)(w);               // [2][NB]
    unsigned int* ovf_cnt = (unsigned int*)(w + 32768);       // [2]
    unsigned int* hcnt    = (unsigned int*)(w + 32776);       // [2]
    float2*       binned  = (float2*)(w + 65536);             // [2][NB][CAP]
    float2*       ovf     = (float2*)(w + 8454144);           // [2][OCAP]
    float2*       hard    = (float2*)(w + 8486912);           // [2][HCAP]

    k_zero<<<(2 * NB + 4 + 255) / 256, 256, 0, stream>>>(cnt, out);
    k_scatter<<<(2 * NPTS) / 256, 256, 0, stream>>>(pc, ref, cnt, ovf_cnt, hcnt,
                                                    binned, ovf, hard);
    // NB cells / 4 waves = 1024 x-blocks, y = dir
    k_query<<<dim3(NB / 4, 2), 256, 0, stream>>>(cnt, ovf_cnt, hcnt,
                                                 binned, ovf, hard, out);
    k_brute<<<256, 256, 0, stream>>>(pc, ref, hcnt, hard, out);
}